// Round 1
// baseline (22760.797 us; speedup 1.0000x reference)
//
#include <hip/hip_runtime.h>
#include <stdint.h>
#include <stddef.h>

typedef uint32_t u32;

// ---------------- problem constants (fixed by reference file) ----------------
#define NB    256      // batch B
#define LFULL 412      // L
#define NCH   3        // C
#define CTX   336      // context_length
#define NSAMP 100      // n_samples
#define TM1   383      // T-1 (T = L - MAX_LAG = 384)
#define HID   64
#define NIN   15
#define RTOT  25600    // NB*NSAMP
#define NCTXS 8601600u // RTOT*CTX
#define NSTEP 47       // H-1

// JAX threefry mode: 1 = partitionable (default since jax ~0.4.30), 0 = legacy iota-split.
// If this round fails with absmax ~0.4 spread everywhere, flip this to 0.
#define JAX_PARTITIONABLE 1

__device__ const int c_LAGS[10] = {1,2,3,4,5,6,7,14,21,28};

// ---------------- threefry2x32 (matches jax._src.prng) ----------------
__host__ __device__ inline void tf2x32(u32 k0, u32 k1, u32 x0, u32 x1, u32& o0, u32& o1) {
  const u32 ks2 = k0 ^ k1 ^ 0x1BD11BDAu;
#define TFR(r) { x0 += x1; x1 = (x1 << (r)) | (x1 >> (32 - (r))); x1 ^= x0; }
  x0 += k0; x1 += k1;
  TFR(13) TFR(15) TFR(26) TFR(6)
  x0 += k1; x1 += ks2 + 1u;
  TFR(17) TFR(29) TFR(16) TFR(24)
  x0 += ks2; x1 += k0 + 2u;
  TFR(13) TFR(15) TFR(26) TFR(6)
  x0 += k0; x1 += k1 + 3u;
  TFR(17) TFR(29) TFR(16) TFR(24)
  x0 += k1; x1 += ks2 + 4u;
  TFR(13) TFR(15) TFR(26) TFR(6)
  x0 += ks2; x1 += k0 + 5u;
#undef TFR
  o0 = x0; o1 = x1;
}

// word j of flattened legacy split(key, n) output (flat length 2n)
__host__ __device__ inline u32 split_word_legacy(u32 k0, u32 k1, u32 n, u32 j) {
  u32 o0, o1;
  if (j < n) { tf2x32(k0, k1, j, n + j, o0, o1); return o0; }
  tf2x32(k0, k1, j - n, j, o0, o1); return o1;
}

// i-th subkey of jax.random.split(key, n)
__host__ __device__ inline void jx_subkey(u32 k0, u32 k1, u32 n, u32 i, u32& s0, u32& s1) {
#if JAX_PARTITIONABLE
  (void)n; tf2x32(k0, k1, 0u, i, s0, s1);
#else
  s0 = split_word_legacy(k0, k1, n, 2u * i);
  s1 = split_word_legacy(k0, k1, n, 2u * i + 1u);
#endif
}

// element i of jax random_bits(key, 32, shape) with prod(shape)=n
__device__ inline u32 jx_bits(u32 k0, u32 k1, u32 n, u32 i) {
#if JAX_PARTITIONABLE
  (void)n; u32 o0, o1; tf2x32(k0, k1, 0u, i, o0, o1); return o0 ^ o1;
#else
  u32 o0, o1;
  if (n == 1u) { tf2x32(k0, k1, 0u, 0u, o0, o1); return o0; }  // odd-size pad path
  const u32 h = n >> 1;
  if (i < h) { tf2x32(k0, k1, i, h + i, o0, o1); return o0; }
  tf2x32(k0, k1, i - h, i, o0, o1); return o1;
#endif
}

// ---------------- JAX-exact float transforms ----------------
__device__ inline float jax_erfinv(float x) {  // XLA ErfInv32 (Giles)
#pragma clang fp contract(off)
  float w = -log1pf(-x * x);
  float p;
  if (w < 5.0f) {
    w = w - 2.5f;
    p = 2.81022636e-08f;
    p = 3.43273939e-07f + p * w;
    p = -3.5233877e-06f + p * w;
    p = -4.39150654e-06f + p * w;
    p = 0.00021858087f + p * w;
    p = -0.00125372503f + p * w;
    p = -0.00417768164f + p * w;
    p = 0.246640727f + p * w;
    p = 1.50140941f + p * w;
  } else {
    w = sqrtf(w) - 3.0f;
    p = -0.000200214257f;
    p = 0.000100950558f + p * w;
    p = 0.00134934322f + p * w;
    p = -0.00367342844f + p * w;
    p = 0.00573950773f + p * w;
    p = -0.0076224613f + p * w;
    p = 0.00943887047f + p * w;
    p = 1.00167406f + p * w;
    p = 2.83297682f + p * w;
  }
  return p * x;
}

__device__ inline float u01_from_bits(u32 bits) {  // uniform(key,(),f32,0,1)
  return __uint_as_float((bits >> 9) | 0x3f800000u) - 1.0f;
}

__device__ inline float normal_from_bits(u32 bits) {  // jax.random.normal element
#pragma clang fp contract(off)
  const float lo = -0.99999994f;  // nextafter(-1,0); span (1-lo) rounds to 2.0f
  const float u = u01_from_bits(bits);
  float r = u * 2.0f + lo;
  r = fmaxf(lo, r);
  return 1.41421356f * jax_erfinv(r);  // float32(sqrt(2))
}

// jax.random.gamma -> _gamma_one(key, alpha) (Marsaglia-Tsang + JAX split sequencing)
__device__ float jax_gamma_one(u32 k0, u32 k1, float alpha) {
#pragma clang fp contract(off)
  const bool boost_mask = (alpha >= 1.0f);
  const float alpha_orig = alpha;
  const float a = boost_mask ? alpha : (alpha + 1.0f);
  const float d = a - 0.33333334f;
  const float c = 0.33333334f / sqrtf(d);
  u32 K0, K1, S0, S1;
  jx_subkey(k0, k1, 2u, 0u, K0, K1);  // key, subkey = split(key)
  jx_subkey(k0, k1, 2u, 1u, S0, S1);
  float u_boost = 1.0f;
  if (!boost_mask) u_boost = u01_from_bits(jx_bits(S0, S1, 1u, 0u));
  float X = 0.0f, V = 1.0f, U = 2.0f;  // init chosen so cond is true
  while (true) {
    if (!(U >= 1.0f - 0.0331f * (X * X))) break;
    if (!(logf(U) >= 0.5f * X + d * ((1.0f - V) + logf(V)))) break;
    u32 nk0, nk1, xk0, xk1, uk0, uk1;
    jx_subkey(K0, K1, 3u, 0u, nk0, nk1);  // key, x_key, U_key = split(key, 3)
    jx_subkey(K0, K1, 3u, 1u, xk0, xk1);
    jx_subkey(K0, K1, 3u, 2u, uk0, uk1);
    K0 = nk0; K1 = nk1;
    float x, v;
    u32 c0 = xk0, c1 = xk1;
    do {  // draw x until v > 0
      u32 t0, t1, s0, s1;
      jx_subkey(c0, c1, 2u, 0u, t0, t1);
      jx_subkey(c0, c1, 2u, 1u, s0, s1);
      c0 = t0; c1 = t1;
      x = normal_from_bits(jx_bits(s0, s1, 1u, 0u));
      v = 1.0f + x * c;
    } while (v <= 0.0f);
    X = x * x;
    V = (v * v) * v;
    U = u01_from_bits(jx_bits(uk0, uk1, 1u, 0u));
  }
  const float sample = d * V;
  const float boost = boost_mask ? 1.0f : powf(u_boost, 1.0f / alpha_orig);
  return sample * boost;
}

__device__ inline float sigm(float x) { return 1.0f / (1.0f + expf(-x)); }
__device__ inline float softplusf(float x) { return fmaxf(x, 0.0f) + log1pf(expf(-fabsf(x))); }

// ---------------- workspace layout (floats) ----------------
enum : size_t {
  OFF_INP  = 0,                          // NB*TM1*NIN = 1470720
  OFF_CT   = OFF_INP + (size_t)NB * TM1 * NIN,   // 86016
  OFF_TS   = OFF_CT + (size_t)NB * CTX,          // 256
  OFF_LTS  = OFF_TS + NB,                        // 256
  OFF_DF   = OFF_LTS + NB,                       // 86016
  OFF_LOC  = OFF_DF + (size_t)NB * CTX,
  OFF_SC   = OFF_LOC + (size_t)NB * CTX,
  OFF_H0F  = OFF_SC + (size_t)NB * CTX,          // 16384 each
  OFF_C0F  = OFF_H0F + (size_t)NB * HID,
  OFF_H1F  = OFF_C0F + (size_t)NB * HID,
  OFF_C1F  = OFF_H1F + (size_t)NB * HID,
  OFF_YH   = OFF_C1F + (size_t)NB * HID,         // RTOT*TM1 = 9804800
  OFF_H0R  = OFF_YH + (size_t)RTOT * TM1,        // RTOT*HID each
  OFF_C0R  = OFF_H0R + (size_t)RTOT * HID,
  OFF_H1R  = OFF_C0R + (size_t)RTOT * HID,
  OFF_C1R  = OFF_H1R + (size_t)RTOT * HID,
  OFF_BUF  = OFF_C1R + (size_t)RTOT * HID,       // RTOT*28
  OFF_PREV = OFF_BUF + (size_t)RTOT * 28,        // RTOT
  WS_FLOATS = OFF_PREV + RTOT                    // ~19.0M floats ~76 MB
};

// ---------------- kernel 1: tscale + feature build ----------------
__global__ void __launch_bounds__(256) prep_kernel(
    const float* __restrict__ X, const float* __restrict__ emb,
    float* __restrict__ inp, float* __restrict__ ct,
    float* __restrict__ tscale, float* __restrict__ ltscale)
{
  const int b = blockIdx.x, t = threadIdx.x;
  __shared__ float red[256];
  __shared__ float ts_sh;
  const float* Xb = X + (size_t)b * LFULL * NCH;
  float p = fabsf(Xb[(28 + t) * NCH]);
  if (t < 80) p += fabsf(Xb[(28 + 256 + t) * NCH]);
  red[t] = p;
  for (int st = 128; st > 0; st >>= 1) { __syncthreads(); if (t < st) red[t] += red[t + st]; }
  __syncthreads();
  if (t == 0) {
    float ts = red[0] / 336.0f;
    ts = fmaxf(ts, 1e-10f);
    tscale[b] = ts; ltscale[b] = logf(ts); ts_sh = ts;
  }
  __syncthreads();
  const float ts = ts_sh;
  const float lts = logf(ts);
  const float ev = emb[0];
  for (int idx = t; idx < TM1 * NIN; idx += 256) {
    const int tt = idx / NIN, f = idx - tt * NIN;
    float val;
    if (f == 0)       val = (tt < CTX) ? Xb[(28 + tt) * NCH] / ts : 0.0f;
    else if (f <= 10) val = (tt < CTX) ? Xb[(28 + tt - c_LAGS[f - 1]) * NCH] / ts : 0.0f;
    else if (f == 11) val = ev;
    else if (f == 12) val = Xb[(28 + tt) * NCH + 2];
    else if (f == 13) val = lts;
    else              val = Xb[(28 + tt) * NCH + 1];
    inp[(size_t)(b * TM1 + tt) * NIN + f] = val;
    if (f == 0 && tt < CTX) ct[b * CTX + tt] = val;
  }
}

// ---------------- kernel 2: fused 2-layer context LSTM + head ----------------
// one block per batch element; thread t owns gate t (weights register-resident)
__global__ void __launch_bounds__(256) ctx_lstm_kernel(
    const float* __restrict__ inp,
    const float* __restrict__ Wih0, const float* __restrict__ Whh0,
    const float* __restrict__ bih0, const float* __restrict__ bhh0,
    const float* __restrict__ Wih1, const float* __restrict__ Whh1,
    const float* __restrict__ bih1, const float* __restrict__ bhh1,
    const float* __restrict__ wdf, const float* __restrict__ bdfp,
    const float* __restrict__ wloc, const float* __restrict__ blocp,
    const float* __restrict__ wsc, const float* __restrict__ bscp,
    float* __restrict__ dfo, float* __restrict__ loco, float* __restrict__ sco,
    float* __restrict__ h0f, float* __restrict__ c0f,
    float* __restrict__ h1f, float* __restrict__ c1f)
{
  const int b = blockIdx.x, t = threadIdx.x;
  __shared__ float x_s[16], h0_s[64], h1_s[64], g_s[256];
  float wih0[15], whh0[64], wih1[64], whh1[64];
#pragma unroll
  for (int k = 0; k < 15; k++) wih0[k] = Wih0[t * 15 + k];
#pragma unroll
  for (int k = 0; k < 64; k++) whh0[k] = Whh0[t * 64 + k];
#pragma unroll
  for (int k = 0; k < 64; k++) wih1[k] = Wih1[t * 64 + k];
#pragma unroll
  for (int k = 0; k < 64; k++) whh1[k] = Whh1[t * 64 + k];
  const float bi0 = bih0[t], bh0 = bhh0[t], bi1 = bih1[t], bh1 = bhh1[t];
  const float bdf = bdfp[0], bloc = blocp[0], bsc = bscp[0];
  float wdfv = 0.f, wlocv = 0.f, wscv = 0.f;
  float c0 = 0.f, h0 = 0.f, c1 = 0.f, h1 = 0.f;
  if (t < 64) { h0_s[t] = 0.f; h1_s[t] = 0.f; wdfv = wdf[t]; wlocv = wloc[t]; wscv = wsc[t]; }
  __syncthreads();
  for (int tt = 0; tt < CTX; tt++) {
    if (t < 15) x_s[t] = inp[(size_t)(b * TM1 + tt) * NIN + t];
    __syncthreads();
    {
      float a = 0.f;
#pragma unroll
      for (int k = 0; k < 15; k++) a += wih0[k] * x_s[k];
      a += bi0;
      float a2 = 0.f;
#pragma unroll
      for (int k = 0; k < 64; k++) a2 += whh0[k] * h0_s[k];
      g_s[t] = (a + a2) + bh0;
    }
    __syncthreads();
    if (t < 64) {
      const float gi = g_s[t], gf = g_s[64 + t], gg = g_s[128 + t], go = g_s[192 + t];
      c0 = sigm(gf) * c0 + sigm(gi) * tanhf(gg);
      h0 = sigm(go) * tanhf(c0);
      h0_s[t] = h0;
    }
    __syncthreads();
    {
      float a = 0.f;
#pragma unroll
      for (int k = 0; k < 64; k++) a += wih1[k] * h0_s[k];
      a += bi1;
      float a2 = 0.f;
#pragma unroll
      for (int k = 0; k < 64; k++) a2 += whh1[k] * h1_s[k];
      g_s[t] = (a + a2) + bh1;
    }
    __syncthreads();
    if (t < 64) {
      const float gi = g_s[t], gf = g_s[64 + t], gg = g_s[128 + t], go = g_s[192 + t];
      c1 = sigm(gf) * c1 + sigm(gi) * tanhf(gg);
      h1 = sigm(go) * tanhf(c1);
      h1_s[t] = h1;
      float pd = h1 * wdfv, pl = h1 * wlocv, ps = h1 * wscv;
#pragma unroll
      for (int off = 32; off > 0; off >>= 1) {
        pd += __shfl_down(pd, off, 64);
        pl += __shfl_down(pl, off, 64);
        ps += __shfl_down(ps, off, 64);
      }
      if (t == 0) {
        dfo[b * CTX + tt]  = 2.0f + softplusf(pd + bdf);
        loco[b * CTX + tt] = pl + bloc;
        sco[b * CTX + tt]  = softplusf(ps + bsc);
      }
    }
    __syncthreads();
  }
  if (t < 64) { h0f[b * 64 + t] = h0; c0f[b * 64 + t] = c0; h1f[b * 64 + t] = h1; c1f[b * 64 + t] = c1; }
}

// ---------------- kernel 3: context sampling (y_ctx) ----------------
__global__ void __launch_bounds__(256) ctx_sample_kernel(
    const float* __restrict__ df, const float* __restrict__ loc, const float* __restrict__ sc,
    const float* __restrict__ tscale, float* __restrict__ yhat,
    u32 kz0, u32 kz1, u32 kg0, u32 kg1)
{
  const int i = blockIdx.x * 256 + threadIdx.x;   // < NCTXS
  const int r = i / CTX, t = i - r * CTX;
  const int b = r / NSAMP;
  const float dfv = df[b * CTX + t], lv = loc[b * CTX + t], sv = sc[b * CTX + t];
  const float z = normal_from_bits(jx_bits(kz0, kz1, NCTXS, (u32)i));
  u32 gk0, gk1;
  jx_subkey(kg0, kg1, NCTXS, (u32)i, gk0, gk1);
  const float g = jax_gamma_one(gk0, gk1, dfv * 0.5f);
  const float y = (lv + sv * (z * sqrtf(dfv / (2.0f * g)))) * tscale[b];
  yhat[(size_t)r * TM1 + t] = y;
}

// ---------------- kernel 4: decode state init ----------------
__global__ void __launch_bounds__(256) dec_init_kernel(
    const float* __restrict__ h0f, const float* __restrict__ c0f,
    const float* __restrict__ h1f, const float* __restrict__ c1f,
    const float* __restrict__ ct, const float* __restrict__ yhat,
    float* __restrict__ h0r, float* __restrict__ c0r,
    float* __restrict__ h1r, float* __restrict__ c1r,
    float* __restrict__ bufg, float* __restrict__ prevg)
{
  const int idx = blockIdx.x * 256 + threadIdx.x;  // over RTOT*64
  const int r = idx >> 6, j = idx & 63;
  const int b = r / NSAMP;
  h0r[idx] = h0f[b * 64 + j];
  c0r[idx] = c0f[b * 64 + j];
  h1r[idx] = h1f[b * 64 + j];
  c1r[idx] = c1f[b * 64 + j];
  if (j < 28) bufg[r * 28 + j] = ct[b * CTX + (335 - j)];  // past_target[:, :28]
  if (j == 0) prevg[r] = yhat[(size_t)r * TM1 + 335];      // y_ctx[:, -1]
}

// ---------------- kernel 5: one autoregressive decode step ----------------
// 512 blocks x 50 rows; phase1 = LSTM+head per row, phase2 = parallel sampling
__global__ void __launch_bounds__(256) dec_step_kernel(
    const float* __restrict__ inp, const float* __restrict__ tscale,
    const float* __restrict__ Wih0, const float* __restrict__ Whh0,
    const float* __restrict__ bih0, const float* __restrict__ bhh0,
    const float* __restrict__ Wih1, const float* __restrict__ Whh1,
    const float* __restrict__ bih1, const float* __restrict__ bhh1,
    const float* __restrict__ wdf, const float* __restrict__ bdfp,
    const float* __restrict__ wloc, const float* __restrict__ blocp,
    const float* __restrict__ wsc, const float* __restrict__ bscp,
    float* __restrict__ h0r, float* __restrict__ c0r,
    float* __restrict__ h1r, float* __restrict__ c1r,
    float* __restrict__ bufg, float* __restrict__ prevg, float* __restrict__ yhat,
    int s, u32 kz0, u32 kz1, u32 kg0, u32 kg1)
{
  const int t = threadIdx.x;
  __shared__ float x_s[16], h0_s[64], h1_s[64], g_s[256];
  __shared__ float dfL[50], locL[50], scL[50];
  float wih0[15], whh0[64], wih1[64], whh1[64];
#pragma unroll
  for (int k = 0; k < 15; k++) wih0[k] = Wih0[t * 15 + k];
#pragma unroll
  for (int k = 0; k < 64; k++) whh0[k] = Whh0[t * 64 + k];
#pragma unroll
  for (int k = 0; k < 64; k++) wih1[k] = Wih1[t * 64 + k];
#pragma unroll
  for (int k = 0; k < 64; k++) wih1[k] = wih1[k], whh1[k] = Whh1[t * 64 + k];
  const float bi0 = bih0[t], bh0 = bhh0[t], bi1 = bih1[t], bh1 = bhh1[t];
  const float bdf = bdfp[0], bloc = blocp[0], bsc = bscp[0];
  float wdfv = 0.f, wlocv = 0.f, wscv = 0.f;
  if (t < 64) { wdfv = wdf[t]; wlocv = wloc[t]; wscv = wsc[t]; }

  const int base = blockIdx.x * 50;
  for (int i = 0; i < 50; i++) {
    const int r = base + i;
    const int b = r / NSAMP;
    float nsv = 0.f, oldb = 0.f;
    if (t == 0)       { nsv = prevg[r] / tscale[b]; x_s[0] = nsv; }
    else if (t <= 10) x_s[t] = bufg[r * 28 + (c_LAGS[t - 1] - 1)];
    else if (t < 15)  x_s[t] = inp[(size_t)(b * TM1 + CTX + s) * NIN + t];
    if (t >= 32 && t < 59) oldb = bufg[r * 28 + (t - 32)];  // old buf[0..26]
    if (t < 64)           h0_s[t]      = h0r[(size_t)r * 64 + t];
    else if (t < 128)     h1_s[t - 64] = h1r[(size_t)r * 64 + (t - 64)];
    __syncthreads();
    {  // layer-0 gates
      float a = 0.f;
#pragma unroll
      for (int k = 0; k < 15; k++) a += wih0[k] * x_s[k];
      a += bi0;
      float a2 = 0.f;
#pragma unroll
      for (int k = 0; k < 64; k++) a2 += whh0[k] * h0_s[k];
      g_s[t] = (a + a2) + bh0;
    }
    // lag-buffer shift (all reads happened before the barrier above)
    if (t == 0) bufg[r * 28] = nsv;
    if (t >= 32 && t < 59) bufg[r * 28 + (t - 32) + 1] = oldb;
    __syncthreads();
    if (t < 64) {  // layer-0 update
      const float gi = g_s[t], gf = g_s[64 + t], gg = g_s[128 + t], go = g_s[192 + t];
      float c0 = c0r[(size_t)r * 64 + t];
      c0 = sigm(gf) * c0 + sigm(gi) * tanhf(gg);
      const float h0 = sigm(go) * tanhf(c0);
      c0r[(size_t)r * 64 + t] = c0;
      h0r[(size_t)r * 64 + t] = h0;
      h0_s[t] = h0;
    }
    __syncthreads();
    {  // layer-1 gates
      float a = 0.f;
#pragma unroll
      for (int k = 0; k < 64; k++) a += wih1[k] * h0_s[k];
      a += bi1;
      float a2 = 0.f;
#pragma unroll
      for (int k = 0; k < 64; k++) a2 += whh1[k] * h1_s[k];
      g_s[t] = (a + a2) + bh1;
    }
    __syncthreads();
    if (t < 64) {  // layer-1 update + head
      const float gi = g_s[t], gf = g_s[64 + t], gg = g_s[128 + t], go = g_s[192 + t];
      float c1 = c1r[(size_t)r * 64 + t];
      c1 = sigm(gf) * c1 + sigm(gi) * tanhf(gg);
      const float h1 = sigm(go) * tanhf(c1);
      c1r[(size_t)r * 64 + t] = c1;
      h1r[(size_t)r * 64 + t] = h1;
      float pd = h1 * wdfv, pl = h1 * wlocv, ps = h1 * wscv;
#pragma unroll
      for (int off = 32; off > 0; off >>= 1) {
        pd += __shfl_down(pd, off, 64);
        pl += __shfl_down(pl, off, 64);
        ps += __shfl_down(ps, off, 64);
      }
      if (t == 0) {
        dfL[i]  = 2.0f + softplusf(pd + bdf);
        locL[i] = pl + bloc;
        scL[i]  = softplusf(ps + bsc);
      }
    }
    __syncthreads();
  }
  // phase 2: sample all 50 rows in parallel
  if (t < 50) {
    const int r = base + t;
    const int b = r / NSAMP;
    const float dfv = dfL[t], lv = locL[t], sv = scL[t];
    const float z = normal_from_bits(jx_bits(kz0, kz1, RTOT, (u32)r));
    u32 gk0, gk1;
    jx_subkey(kg0, kg1, RTOT, (u32)r, gk0, gk1);
    const float g = jax_gamma_one(gk0, gk1, dfv * 0.5f);
    const float y = (lv + sv * (z * sqrtf(dfv / (2.0f * g)))) * tscale[b];
    yhat[(size_t)r * TM1 + CTX + s] = y;
    prevg[r] = y;
  }
}

// ---------------- kernel 6: median over 100 samples per (b,t) ----------------
__global__ void __launch_bounds__(256) median_kernel(
    const float* __restrict__ yhat, float* __restrict__ out)
{
  __shared__ float vals[4][100];
  const int wave = threadIdx.x >> 6, lane = threadIdx.x & 63;
  const int cell = blockIdx.x * 4 + wave;          // NB*TM1 = 98048 = 24512*4 exactly
  const int b = cell / TM1, t = cell - b * TM1;
  const float* basep = yhat + (size_t)b * NSAMP * TM1 + t;
  const float v1 = basep[(size_t)lane * TM1];
  vals[wave][lane] = v1;
  float v2 = 0.f;
  if (lane < 36) { v2 = basep[(size_t)(64 + lane) * TM1]; vals[wave][64 + lane] = v2; }
  __syncthreads();
  int cl1 = 0, ce1 = 0, cl2 = 0, ce2 = 0;
  for (int j = 0; j < 100; j++) {
    const float w = vals[wave][j];
    cl1 += (w < v1); ce1 += (w == v1);
    cl2 += (w < v2); ce2 += (w == v2);
  }
  if (cl1 <= 49 && 49 < cl1 + ce1) out[cell] = v1;                 // rank-49 value
  if (lane < 36 && cl2 <= 49 && 49 < cl2 + ce2) out[cell] = v2;
}

// ---------------- launch ----------------
extern "C" void kernel_launch(void* const* d_in, const int* in_sizes, int n_in,
                              void* d_out, int out_size, void* d_ws, size_t ws_size,
                              hipStream_t stream) {
  (void)in_sizes; (void)n_in; (void)out_size; (void)ws_size;
  const float* X     = (const float*)d_in[0];
  // d_in[1] = pad_mask (all True in this problem) — intentionally unused
  const float* Wih0  = (const float*)d_in[2];
  const float* Whh0  = (const float*)d_in[3];
  const float* bih0  = (const float*)d_in[4];
  const float* bhh0  = (const float*)d_in[5];
  const float* Wih1  = (const float*)d_in[6];
  const float* Whh1  = (const float*)d_in[7];
  const float* bih1  = (const float*)d_in[8];
  const float* bhh1  = (const float*)d_in[9];
  const float* wdf   = (const float*)d_in[10];
  const float* bdf   = (const float*)d_in[11];
  const float* wloc  = (const float*)d_in[12];
  const float* bloc  = (const float*)d_in[13];
  const float* wsc   = (const float*)d_in[14];
  const float* bsc   = (const float*)d_in[15];
  const float* emb   = (const float*)d_in[16];
  // d_in[17..19] = H, context_length, n_samples — compile-time constants here

  float* wsf = (float*)d_ws;
  float* inp  = wsf + OFF_INP;
  float* ct   = wsf + OFF_CT;
  float* ts   = wsf + OFF_TS;
  float* lts  = wsf + OFF_LTS;
  float* dfp  = wsf + OFF_DF;
  float* locp = wsf + OFF_LOC;
  float* scp  = wsf + OFF_SC;
  float* h0f  = wsf + OFF_H0F;
  float* c0f  = wsf + OFF_C0F;
  float* h1f  = wsf + OFF_H1F;
  float* c1f  = wsf + OFF_C1F;
  float* yhat = wsf + OFF_YH;
  float* h0r  = wsf + OFF_H0R;
  float* c0r  = wsf + OFF_C0R;
  float* h1r  = wsf + OFF_H1R;
  float* c1r  = wsf + OFF_C1R;
  float* bufg = wsf + OFF_BUF;
  float* prev = wsf + OFF_PREV;

  // ---- host-side key derivation (pure, identical every call) ----
  const u32 key0 = 0u, key1 = 42u;                 // jax.random.key(42)
  u32 kc0, kc1, kl0, kl1;
  jx_subkey(key0, key1, 2u, 0u, kc0, kc1);         // k_ctx
  jx_subkey(key0, key1, 2u, 1u, kl0, kl1);         // k_loop
  u32 kz0, kz1, kg0, kg1;
  jx_subkey(kc0, kc1, 2u, 0u, kz0, kz1);           // kz for context noise
  jx_subkey(kc0, kc1, 2u, 1u, kg0, kg1);           // kg for context gamma

  prep_kernel<<<NB, 256, 0, stream>>>(X, emb, inp, ct, ts, lts);
  ctx_lstm_kernel<<<NB, 256, 0, stream>>>(inp, Wih0, Whh0, bih0, bhh0, Wih1, Whh1, bih1, bhh1,
                                          wdf, bdf, wloc, bloc, wsc, bsc,
                                          dfp, locp, scp, h0f, c0f, h1f, c1f);
  ctx_sample_kernel<<<NCTXS / 256, 256, 0, stream>>>(dfp, locp, scp, ts, yhat, kz0, kz1, kg0, kg1);
  dec_init_kernel<<<(RTOT * 64) / 256, 256, 0, stream>>>(h0f, c0f, h1f, c1f, ct, yhat,
                                                         h0r, c0r, h1r, c1r, bufg, prev);
  for (int s = 0; s < NSTEP; s++) {
    u32 ks0, ks1;
    jx_subkey(kl0, kl1, (u32)NSTEP, (u32)s, ks0, ks1);  // keys[s]
    u32 skz0, skz1, skg0, skg1;
    jx_subkey(ks0, ks1, 2u, 0u, skz0, skz1);
    jx_subkey(ks0, ks1, 2u, 1u, skg0, skg1);
    dec_step_kernel<<<512, 256, 0, stream>>>(inp, ts, Wih0, Whh0, bih0, bhh0, Wih1, Whh1,
                                             bih1, bhh1, wdf, bdf, wloc, bloc, wsc, bsc,
                                             h0r, c0r, h1r, c1r, bufg, prev, yhat,
                                             s, skz0, skz1, skg0, skg1);
  }
  median_kernel<<<(NB * TM1) / 4, 256, 0, stream>>>(yhat, (float*)d_out);
}

// Round 2
// 16738.490 us; speedup vs baseline: 1.3598x; 1.3598x over previous
//
#include <hip/hip_runtime.h>
#include <stdint.h>
#include <stddef.h>

typedef uint32_t u32;

// ---------------- problem constants (fixed by reference file) ----------------
#define NB    256      // batch B
#define LFULL 412      // L
#define NCH   3        // C
#define CTX   336      // context_length
#define NSAMP 100      // n_samples
#define TM1   383      // T-1 (T = L - MAX_LAG = 384)
#define HID   64
#define NIN   15
#define RTOT  25600    // NB*NSAMP
#define NCTXS 8601600u // RTOT*CTX
#define NSTEP 47       // H-1

#define JAX_PARTITIONABLE 1

__device__ const int c_LAGS[10] = {1,2,3,4,5,6,7,14,21,28};

// ---------------- threefry2x32 (matches jax._src.prng) ----------------
__host__ __device__ inline void tf2x32(u32 k0, u32 k1, u32 x0, u32 x1, u32& o0, u32& o1) {
  const u32 ks2 = k0 ^ k1 ^ 0x1BD11BDAu;
#define TFR(r) { x0 += x1; x1 = (x1 << (r)) | (x1 >> (32 - (r))); x1 ^= x0; }
  x0 += k0; x1 += k1;
  TFR(13) TFR(15) TFR(26) TFR(6)
  x0 += k1; x1 += ks2 + 1u;
  TFR(17) TFR(29) TFR(16) TFR(24)
  x0 += ks2; x1 += k0 + 2u;
  TFR(13) TFR(15) TFR(26) TFR(6)
  x0 += k0; x1 += k1 + 3u;
  TFR(17) TFR(29) TFR(16) TFR(24)
  x0 += k1; x1 += ks2 + 4u;
  TFR(13) TFR(15) TFR(26) TFR(6)
  x0 += ks2; x1 += k0 + 5u;
#undef TFR
  o0 = x0; o1 = x1;
}

__host__ __device__ inline u32 split_word_legacy(u32 k0, u32 k1, u32 n, u32 j) {
  u32 o0, o1;
  if (j < n) { tf2x32(k0, k1, j, n + j, o0, o1); return o0; }
  tf2x32(k0, k1, j - n, j, o0, o1); return o1;
}

__host__ __device__ inline void jx_subkey(u32 k0, u32 k1, u32 n, u32 i, u32& s0, u32& s1) {
#if JAX_PARTITIONABLE
  (void)n; tf2x32(k0, k1, 0u, i, s0, s1);
#else
  s0 = split_word_legacy(k0, k1, n, 2u * i);
  s1 = split_word_legacy(k0, k1, n, 2u * i + 1u);
#endif
}

__device__ inline u32 jx_bits(u32 k0, u32 k1, u32 n, u32 i) {
#if JAX_PARTITIONABLE
  (void)n; u32 o0, o1; tf2x32(k0, k1, 0u, i, o0, o1); return o0 ^ o1;
#else
  u32 o0, o1;
  if (n == 1u) { tf2x32(k0, k1, 0u, 0u, o0, o1); return o0; }
  const u32 h = n >> 1;
  if (i < h) { tf2x32(k0, k1, i, h + i, o0, o1); return o0; }
  tf2x32(k0, k1, i - h, i, o0, o1); return o1;
#endif
}

// ---------------- JAX-exact float transforms ----------------
__device__ inline float jax_erfinv(float x) {
#pragma clang fp contract(off)
  float w = -log1pf(-x * x);
  float p;
  if (w < 5.0f) {
    w = w - 2.5f;
    p = 2.81022636e-08f;
    p = 3.43273939e-07f + p * w;
    p = -3.5233877e-06f + p * w;
    p = -4.39150654e-06f + p * w;
    p = 0.00021858087f + p * w;
    p = -0.00125372503f + p * w;
    p = -0.00417768164f + p * w;
    p = 0.246640727f + p * w;
    p = 1.50140941f + p * w;
  } else {
    w = sqrtf(w) - 3.0f;
    p = -0.000200214257f;
    p = 0.000100950558f + p * w;
    p = 0.00134934322f + p * w;
    p = -0.00367342844f + p * w;
    p = 0.00573950773f + p * w;
    p = -0.0076224613f + p * w;
    p = 0.00943887047f + p * w;
    p = 1.00167406f + p * w;
    p = 2.83297682f + p * w;
  }
  return p * x;
}

__device__ inline float u01_from_bits(u32 bits) {
  return __uint_as_float((bits >> 9) | 0x3f800000u) - 1.0f;
}

__device__ inline float normal_from_bits(u32 bits) {
#pragma clang fp contract(off)
  const float lo = -0.99999994f;
  const float u = u01_from_bits(bits);
  float r = u * 2.0f + lo;
  r = fmaxf(lo, r);
  return 1.41421356f * jax_erfinv(r);
}

__device__ float jax_gamma_one(u32 k0, u32 k1, float alpha) {
#pragma clang fp contract(off)
  const bool boost_mask = (alpha >= 1.0f);
  const float alpha_orig = alpha;
  const float a = boost_mask ? alpha : (alpha + 1.0f);
  const float d = a - 0.33333334f;
  const float c = 0.33333334f / sqrtf(d);
  u32 K0, K1, S0, S1;
  jx_subkey(k0, k1, 2u, 0u, K0, K1);
  jx_subkey(k0, k1, 2u, 1u, S0, S1);
  float u_boost = 1.0f;
  if (!boost_mask) u_boost = u01_from_bits(jx_bits(S0, S1, 1u, 0u));
  float X = 0.0f, V = 1.0f, U = 2.0f;
  while (true) {
    if (!(U >= 1.0f - 0.0331f * (X * X))) break;
    if (!(logf(U) >= 0.5f * X + d * ((1.0f - V) + logf(V)))) break;
    u32 nk0, nk1, xk0, xk1, uk0, uk1;
    jx_subkey(K0, K1, 3u, 0u, nk0, nk1);
    jx_subkey(K0, K1, 3u, 1u, xk0, xk1);
    jx_subkey(K0, K1, 3u, 2u, uk0, uk1);
    K0 = nk0; K1 = nk1;
    float x, v;
    u32 c0 = xk0, c1 = xk1;
    do {
      u32 t0, t1, s0, s1;
      jx_subkey(c0, c1, 2u, 0u, t0, t1);
      jx_subkey(c0, c1, 2u, 1u, s0, s1);
      c0 = t0; c1 = t1;
      x = normal_from_bits(jx_bits(s0, s1, 1u, 0u));
      v = 1.0f + x * c;
    } while (v <= 0.0f);
    X = x * x;
    V = (v * v) * v;
    U = u01_from_bits(jx_bits(uk0, uk1, 1u, 0u));
  }
  const float sample = d * V;
  const float boost = boost_mask ? 1.0f : powf(u_boost, 1.0f / alpha_orig);
  return sample * boost;
}

__device__ inline float sigm(float x) { return 1.0f / (1.0f + expf(-x)); }
__device__ inline float softplusf(float x) { return fmaxf(x, 0.0f) + log1pf(expf(-fabsf(x))); }

// ---------------- workspace layout (floats) ----------------
enum : size_t {
  OFF_INP  = 0,
  OFF_CT   = OFF_INP + (size_t)NB * TM1 * NIN,
  OFF_TS   = OFF_CT + (size_t)NB * CTX,
  OFF_LTS  = OFF_TS + NB,
  OFF_DF   = OFF_LTS + NB,
  OFF_LOC  = OFF_DF + (size_t)NB * CTX,
  OFF_SC   = OFF_LOC + (size_t)NB * CTX,
  OFF_H0F  = OFF_SC + (size_t)NB * CTX,
  OFF_C0F  = OFF_H0F + (size_t)NB * HID,
  OFF_H1F  = OFF_C0F + (size_t)NB * HID,
  OFF_C1F  = OFF_H1F + (size_t)NB * HID,
  OFF_YH   = OFF_C1F + (size_t)NB * HID,
  OFF_H0R  = OFF_YH + (size_t)RTOT * TM1,
  OFF_C0R  = OFF_H0R + (size_t)RTOT * HID,
  OFF_H1R  = OFF_C0R + (size_t)RTOT * HID,
  OFF_C1R  = OFF_H1R + (size_t)RTOT * HID,
  OFF_BUF  = OFF_C1R + (size_t)RTOT * HID,
  OFF_PREV = OFF_BUF + (size_t)RTOT * 28,
  WS_FLOATS = OFF_PREV + RTOT
};

// ---------------- kernel 1: tscale + feature build ----------------
__global__ void __launch_bounds__(256) prep_kernel(
    const float* __restrict__ X, const float* __restrict__ emb,
    float* __restrict__ inp, float* __restrict__ ct,
    float* __restrict__ tscale, float* __restrict__ ltscale)
{
  const int b = blockIdx.x, t = threadIdx.x;
  __shared__ float red[256];
  __shared__ float ts_sh;
  const float* Xb = X + (size_t)b * LFULL * NCH;
  float p = fabsf(Xb[(28 + t) * NCH]);
  if (t < 80) p += fabsf(Xb[(28 + 256 + t) * NCH]);
  red[t] = p;
  for (int st = 128; st > 0; st >>= 1) { __syncthreads(); if (t < st) red[t] += red[t + st]; }
  __syncthreads();
  if (t == 0) {
    float ts = red[0] / 336.0f;
    ts = fmaxf(ts, 1e-10f);
    tscale[b] = ts; ltscale[b] = logf(ts); ts_sh = ts;
  }
  __syncthreads();
  const float ts = ts_sh;
  const float lts = logf(ts);
  const float ev = emb[0];
  for (int idx = t; idx < TM1 * NIN; idx += 256) {
    const int tt = idx / NIN, f = idx - tt * NIN;
    float val;
    if (f == 0)       val = (tt < CTX) ? Xb[(28 + tt) * NCH] / ts : 0.0f;
    else if (f <= 10) val = (tt < CTX) ? Xb[(28 + tt - c_LAGS[f - 1]) * NCH] / ts : 0.0f;
    else if (f == 11) val = ev;
    else if (f == 12) val = Xb[(28 + tt) * NCH + 2];
    else if (f == 13) val = lts;
    else              val = Xb[(28 + tt) * NCH + 1];
    inp[(size_t)(b * TM1 + tt) * NIN + f] = val;
    if (f == 0 && tt < CTX) ct[b * CTX + tt] = val;
  }
}

// ---------------- kernel 2: fused 2-layer context LSTM + head ----------------
__global__ void __launch_bounds__(256) ctx_lstm_kernel(
    const float* __restrict__ inp,
    const float* __restrict__ Wih0, const float* __restrict__ Whh0,
    const float* __restrict__ bih0, const float* __restrict__ bhh0,
    const float* __restrict__ Wih1, const float* __restrict__ Whh1,
    const float* __restrict__ bih1, const float* __restrict__ bhh1,
    const float* __restrict__ wdf, const float* __restrict__ bdfp,
    const float* __restrict__ wloc, const float* __restrict__ blocp,
    const float* __restrict__ wsc, const float* __restrict__ bscp,
    float* __restrict__ dfo, float* __restrict__ loco, float* __restrict__ sco,
    float* __restrict__ h0f, float* __restrict__ c0f,
    float* __restrict__ h1f, float* __restrict__ c1f)
{
  const int b = blockIdx.x, t = threadIdx.x;
  __shared__ float x_s[16], h0_s[64], h1_s[64], g_s[256];
  float wih0[15], whh0[64], wih1[64], whh1[64];
#pragma unroll
  for (int k = 0; k < 15; k++) wih0[k] = Wih0[t * 15 + k];
#pragma unroll
  for (int k = 0; k < 64; k++) whh0[k] = Whh0[t * 64 + k];
#pragma unroll
  for (int k = 0; k < 64; k++) wih1[k] = Wih1[t * 64 + k];
#pragma unroll
  for (int k = 0; k < 64; k++) whh1[k] = Whh1[t * 64 + k];
  const float bi0 = bih0[t], bh0 = bhh0[t], bi1 = bih1[t], bh1 = bhh1[t];
  const float bdf = bdfp[0], bloc = blocp[0], bsc = bscp[0];
  float wdfv = 0.f, wlocv = 0.f, wscv = 0.f;
  float c0 = 0.f, h0 = 0.f, c1 = 0.f, h1 = 0.f;
  if (t < 64) { h0_s[t] = 0.f; h1_s[t] = 0.f; wdfv = wdf[t]; wlocv = wloc[t]; wscv = wsc[t]; }
  __syncthreads();
  for (int tt = 0; tt < CTX; tt++) {
    if (t < 15) x_s[t] = inp[(size_t)(b * TM1 + tt) * NIN + t];
    __syncthreads();
    {
      float a = 0.f;
#pragma unroll
      for (int k = 0; k < 15; k++) a += wih0[k] * x_s[k];
      a += bi0;
      float a2 = 0.f;
#pragma unroll
      for (int k = 0; k < 64; k++) a2 += whh0[k] * h0_s[k];
      g_s[t] = (a + a2) + bh0;
    }
    __syncthreads();
    if (t < 64) {
      const float gi = g_s[t], gf = g_s[64 + t], gg = g_s[128 + t], go = g_s[192 + t];
      c0 = sigm(gf) * c0 + sigm(gi) * tanhf(gg);
      h0 = sigm(go) * tanhf(c0);
      h0_s[t] = h0;
    }
    __syncthreads();
    {
      float a = 0.f;
#pragma unroll
      for (int k = 0; k < 64; k++) a += wih1[k] * h0_s[k];
      a += bi1;
      float a2 = 0.f;
#pragma unroll
      for (int k = 0; k < 64; k++) a2 += whh1[k] * h1_s[k];
      g_s[t] = (a + a2) + bh1;
    }
    __syncthreads();
    if (t < 64) {
      const float gi = g_s[t], gf = g_s[64 + t], gg = g_s[128 + t], go = g_s[192 + t];
      c1 = sigm(gf) * c1 + sigm(gi) * tanhf(gg);
      h1 = sigm(go) * tanhf(c1);
      h1_s[t] = h1;
      float pd = h1 * wdfv, pl = h1 * wlocv, ps = h1 * wscv;
#pragma unroll
      for (int off = 32; off > 0; off >>= 1) {
        pd += __shfl_down(pd, off, 64);
        pl += __shfl_down(pl, off, 64);
        ps += __shfl_down(ps, off, 64);
      }
      if (t == 0) {
        dfo[b * CTX + tt]  = 2.0f + softplusf(pd + bdf);
        loco[b * CTX + tt] = pl + bloc;
        sco[b * CTX + tt]  = softplusf(ps + bsc);
      }
    }
    __syncthreads();
  }
  if (t < 64) { h0f[b * 64 + t] = h0; c0f[b * 64 + t] = c0; h1f[b * 64 + t] = h1; c1f[b * 64 + t] = c1; }
}

// ---------------- kernel 3: context sampling (y_ctx) ----------------
__global__ void __launch_bounds__(256) ctx_sample_kernel(
    const float* __restrict__ df, const float* __restrict__ loc, const float* __restrict__ sc,
    const float* __restrict__ tscale, float* __restrict__ yhat,
    u32 kz0, u32 kz1, u32 kg0, u32 kg1)
{
  const int i = blockIdx.x * 256 + threadIdx.x;
  const int r = i / CTX, t = i - r * CTX;
  const int b = r / NSAMP;
  const float dfv = df[b * CTX + t], lv = loc[b * CTX + t], sv = sc[b * CTX + t];
  const float z = normal_from_bits(jx_bits(kz0, kz1, NCTXS, (u32)i));
  u32 gk0, gk1;
  jx_subkey(kg0, kg1, NCTXS, (u32)i, gk0, gk1);
  const float g = jax_gamma_one(gk0, gk1, dfv * 0.5f);
  const float y = (lv + sv * (z * sqrtf(dfv / (2.0f * g)))) * tscale[b];
  yhat[(size_t)r * TM1 + t] = y;
}

// ---------------- kernel 4: decode state init ----------------
__global__ void __launch_bounds__(256) dec_init_kernel(
    const float* __restrict__ h0f, const float* __restrict__ c0f,
    const float* __restrict__ h1f, const float* __restrict__ c1f,
    const float* __restrict__ ct, const float* __restrict__ yhat,
    float* __restrict__ h0r, float* __restrict__ c0r,
    float* __restrict__ h1r, float* __restrict__ c1r,
    float* __restrict__ bufg, float* __restrict__ prevg)
{
  const int idx = blockIdx.x * 256 + threadIdx.x;
  const int r = idx >> 6, j = idx & 63;
  const int b = r / NSAMP;
  h0r[idx] = h0f[b * 64 + j];
  c0r[idx] = c0f[b * 64 + j];
  h1r[idx] = h1f[b * 64 + j];
  c1r[idx] = c1f[b * 64 + j];
  if (j < 28) bufg[r * 28 + j] = ct[b * CTX + (335 - j)];
  if (j == 0) prevg[r] = yhat[(size_t)r * TM1 + 335];
}

// ---------------- kernel 5: one autoregressive decode step ----------------
// 1600 blocks x 16 rows; rows batched 4-per-barrier-group (wave r owns row r
// of the group in elementwise phases). Weights register-resident, no spills:
// __launch_bounds__(256,2) -> 256 VGPR cap, live set ~240.
__global__ void __launch_bounds__(256, 2) dec_step_kernel(
    const float* __restrict__ inp, const float* __restrict__ tscale,
    const float* __restrict__ Wih0, const float* __restrict__ Whh0,
    const float* __restrict__ bih0, const float* __restrict__ bhh0,
    const float* __restrict__ Wih1, const float* __restrict__ Whh1,
    const float* __restrict__ bih1, const float* __restrict__ bhh1,
    const float* __restrict__ wdf, const float* __restrict__ bdfp,
    const float* __restrict__ wloc, const float* __restrict__ blocp,
    const float* __restrict__ wsc, const float* __restrict__ bscp,
    float* __restrict__ h0r, float* __restrict__ c0r,
    float* __restrict__ h1r, float* __restrict__ c1r,
    float* __restrict__ bufg, float* __restrict__ prevg, float* __restrict__ yhat,
    int s, u32 kz0, u32 kz1, u32 kg0, u32 kg1)
{
  const int t = threadIdx.x;
  const int r = t >> 6, j = t & 63;
  __shared__ __align__(16) float x_s[4][16];
  __shared__ __align__(16) float h0st[4][64];
  __shared__ __align__(16) float h1st[4][64];
  __shared__ __align__(16) float h0nw[4][64];
  __shared__ __align__(16) float g_s[4][256];
  __shared__ float dfL[16], locL[16], scL[16];

  float wih0[16], whh0[64], wih1[64], whh1[64];
#pragma unroll
  for (int k = 0; k < 15; k++) wih0[k] = Wih0[t * 15 + k];
  wih0[15] = 0.0f;  // pad weight; x_s[r][15] is zeroed too
  {
    const float4* W = (const float4*)(Whh0 + t * 64);
#pragma unroll
    for (int k = 0; k < 16; k++) { float4 v = W[k]; whh0[4*k] = v.x; whh0[4*k+1] = v.y; whh0[4*k+2] = v.z; whh0[4*k+3] = v.w; }
  }
  {
    const float4* W = (const float4*)(Wih1 + t * 64);
#pragma unroll
    for (int k = 0; k < 16; k++) { float4 v = W[k]; wih1[4*k] = v.x; wih1[4*k+1] = v.y; wih1[4*k+2] = v.z; wih1[4*k+3] = v.w; }
  }
  {
    const float4* W = (const float4*)(Whh1 + t * 64);
#pragma unroll
    for (int k = 0; k < 16; k++) { float4 v = W[k]; whh1[4*k] = v.x; whh1[4*k+1] = v.y; whh1[4*k+2] = v.z; whh1[4*k+3] = v.w; }
  }
  const float bi0 = bih0[t], bh0 = bhh0[t], bi1 = bih1[t], bh1 = bhh1[t];
  const float bdf = bdfp[0], bloc = blocp[0], bsc = bscp[0];
  const float wdfv = wdf[j], wlocv = wloc[j], wscv = wsc[j];

  const int base = blockIdx.x * 16;

  for (int g = 0; g < 4; g++) {
    const int row = base + g * 4 + r;
    const int b = row / NSAMP;
    const size_t row64 = (size_t)row * 64;

    // ---- phase A: stage x, h-states; read old lag buffer ----
    float nsv = 0.f, ob = 0.f;
    if (j == 0)            { nsv = prevg[row] / tscale[b]; x_s[r][0] = nsv; }
    else if (j <= 10)      x_s[r][j] = bufg[row * 28 + (c_LAGS[j - 1] - 1)];
    else if (j < 15)       x_s[r][j] = inp[(size_t)(b * TM1 + CTX + s) * NIN + j];
    else if (j == 15)      x_s[r][15] = 0.0f;
    else if (j >= 32 && j < 59) ob = bufg[row * 28 + (j - 32)];
    h0st[r][j] = h0r[row64 + j];
    h1st[r][j] = h1r[row64 + j];
    __syncthreads();

    // ---- phase B: layer-0 gates for 4 rows + lag-buffer shift ----
    {
      if (j == 0) bufg[row * 28] = nsv;
      else if (j >= 32 && j < 59) bufg[row * 28 + (j - 32) + 1] = ob;
      float a0 = 0.f, a1 = 0.f, a2 = 0.f, a3 = 0.f;
      const float4* x0 = (const float4*)x_s[0];
      const float4* x1 = (const float4*)x_s[1];
      const float4* x2 = (const float4*)x_s[2];
      const float4* x3 = (const float4*)x_s[3];
#pragma unroll
      for (int k = 0; k < 4; k++) {
        float4 v0 = x0[k], v1 = x1[k], v2 = x2[k], v3 = x3[k];
        a0 += wih0[4*k]*v0.x; a0 += wih0[4*k+1]*v0.y; a0 += wih0[4*k+2]*v0.z; a0 += wih0[4*k+3]*v0.w;
        a1 += wih0[4*k]*v1.x; a1 += wih0[4*k+1]*v1.y; a1 += wih0[4*k+2]*v1.z; a1 += wih0[4*k+3]*v1.w;
        a2 += wih0[4*k]*v2.x; a2 += wih0[4*k+1]*v2.y; a2 += wih0[4*k+2]*v2.z; a2 += wih0[4*k+3]*v2.w;
        a3 += wih0[4*k]*v3.x; a3 += wih0[4*k+1]*v3.y; a3 += wih0[4*k+2]*v3.z; a3 += wih0[4*k+3]*v3.w;
      }
      a0 += bi0; a1 += bi0; a2 += bi0; a3 += bi0;
      float s0 = 0.f, s1 = 0.f, s2 = 0.f, s3 = 0.f;
      const float4* h0 = (const float4*)h0st[0];
      const float4* h1 = (const float4*)h0st[1];
      const float4* h2 = (const float4*)h0st[2];
      const float4* h3 = (const float4*)h0st[3];
#pragma unroll
      for (int k = 0; k < 16; k++) {
        float4 v0 = h0[k], v1 = h1[k], v2 = h2[k], v3 = h3[k];
        s0 += whh0[4*k]*v0.x; s0 += whh0[4*k+1]*v0.y; s0 += whh0[4*k+2]*v0.z; s0 += whh0[4*k+3]*v0.w;
        s1 += whh0[4*k]*v1.x; s1 += whh0[4*k+1]*v1.y; s1 += whh0[4*k+2]*v1.z; s1 += whh0[4*k+3]*v1.w;
        s2 += whh0[4*k]*v2.x; s2 += whh0[4*k+1]*v2.y; s2 += whh0[4*k+2]*v2.z; s2 += whh0[4*k+3]*v2.w;
        s3 += whh0[4*k]*v3.x; s3 += whh0[4*k+1]*v3.y; s3 += whh0[4*k+2]*v3.z; s3 += whh0[4*k+3]*v3.w;
      }
      g_s[0][t] = (a0 + s0) + bh0;
      g_s[1][t] = (a1 + s1) + bh0;
      g_s[2][t] = (a2 + s2) + bh0;
      g_s[3][t] = (a3 + s3) + bh0;
    }
    __syncthreads();

    // ---- phase C: layer-0 cell update (wave r -> row r) ----
    {
      const float gi = g_s[r][j], gf = g_s[r][64 + j], gg = g_s[r][128 + j], go = g_s[r][192 + j];
      float c0 = c0r[row64 + j];
      c0 = sigm(gf) * c0 + sigm(gi) * tanhf(gg);
      const float h0 = sigm(go) * tanhf(c0);
      c0r[row64 + j] = c0;
      h0r[row64 + j] = h0;
      h0nw[r][j] = h0;
    }
    __syncthreads();

    // ---- phase D: layer-1 gates for 4 rows ----
    {
      float a0 = 0.f, a1 = 0.f, a2 = 0.f, a3 = 0.f;
      const float4* p0 = (const float4*)h0nw[0];
      const float4* p1 = (const float4*)h0nw[1];
      const float4* p2 = (const float4*)h0nw[2];
      const float4* p3 = (const float4*)h0nw[3];
#pragma unroll
      for (int k = 0; k < 16; k++) {
        float4 v0 = p0[k], v1 = p1[k], v2 = p2[k], v3 = p3[k];
        a0 += wih1[4*k]*v0.x; a0 += wih1[4*k+1]*v0.y; a0 += wih1[4*k+2]*v0.z; a0 += wih1[4*k+3]*v0.w;
        a1 += wih1[4*k]*v1.x; a1 += wih1[4*k+1]*v1.y; a1 += wih1[4*k+2]*v1.z; a1 += wih1[4*k+3]*v1.w;
        a2 += wih1[4*k]*v2.x; a2 += wih1[4*k+1]*v2.y; a2 += wih1[4*k+2]*v2.z; a2 += wih1[4*k+3]*v2.w;
        a3 += wih1[4*k]*v3.x; a3 += wih1[4*k+1]*v3.y; a3 += wih1[4*k+2]*v3.z; a3 += wih1[4*k+3]*v3.w;
      }
      a0 += bi1; a1 += bi1; a2 += bi1; a3 += bi1;
      float s0 = 0.f, s1 = 0.f, s2 = 0.f, s3 = 0.f;
      const float4* q0 = (const float4*)h1st[0];
      const float4* q1 = (const float4*)h1st[1];
      const float4* q2 = (const float4*)h1st[2];
      const float4* q3 = (const float4*)h1st[3];
#pragma unroll
      for (int k = 0; k < 16; k++) {
        float4 v0 = q0[k], v1 = q1[k], v2 = q2[k], v3 = q3[k];
        s0 += whh1[4*k]*v0.x; s0 += whh1[4*k+1]*v0.y; s0 += whh1[4*k+2]*v0.z; s0 += whh1[4*k+3]*v0.w;
        s1 += whh1[4*k]*v1.x; s1 += whh1[4*k+1]*v1.y; s1 += whh1[4*k+2]*v1.z; s1 += whh1[4*k+3]*v1.w;
        s2 += whh1[4*k]*v2.x; s2 += whh1[4*k+1]*v2.y; s2 += whh1[4*k+2]*v2.z; s2 += whh1[4*k+3]*v2.w;
        s3 += whh1[4*k]*v3.x; s3 += whh1[4*k+1]*v3.y; s3 += whh1[4*k+2]*v3.z; s3 += whh1[4*k+3]*v3.w;
      }
      g_s[0][t] = (a0 + s0) + bh1;
      g_s[1][t] = (a1 + s1) + bh1;
      g_s[2][t] = (a2 + s2) + bh1;
      g_s[3][t] = (a3 + s3) + bh1;
    }
    __syncthreads();

    // ---- phase E: layer-1 update + head (wave r -> row r) ----
    {
      const float gi = g_s[r][j], gf = g_s[r][64 + j], gg = g_s[r][128 + j], go = g_s[r][192 + j];
      float c1 = c1r[row64 + j];
      c1 = sigm(gf) * c1 + sigm(gi) * tanhf(gg);
      const float h1 = sigm(go) * tanhf(c1);
      c1r[row64 + j] = c1;
      h1r[row64 + j] = h1;
      float pd = h1 * wdfv, pl = h1 * wlocv, ps = h1 * wscv;
#pragma unroll
      for (int off = 32; off > 0; off >>= 1) {
        pd += __shfl_down(pd, off, 64);
        pl += __shfl_down(pl, off, 64);
        ps += __shfl_down(ps, off, 64);
      }
      if (j == 0) {
        dfL[g * 4 + r]  = 2.0f + softplusf(pd + bdf);
        locL[g * 4 + r] = pl + bloc;
        scL[g * 4 + r]  = softplusf(ps + bsc);
      }
    }
    __syncthreads();
  }

  // ---- sampling phase: 16 rows ----
  if (t < 16) {
    const int row = base + t;
    const int b = row / NSAMP;
    const float dfv = dfL[t], lv = locL[t], sv = scL[t];
    const float z = normal_from_bits(jx_bits(kz0, kz1, RTOT, (u32)row));
    u32 gk0, gk1;
    jx_subkey(kg0, kg1, RTOT, (u32)row, gk0, gk1);
    const float g = jax_gamma_one(gk0, gk1, dfv * 0.5f);
    const float y = (lv + sv * (z * sqrtf(dfv / (2.0f * g)))) * tscale[b];
    yhat[(size_t)row * TM1 + CTX + s] = y;
    prevg[row] = y;
  }
}

// ---------------- kernel 6: median over 100 samples per (b,t) ----------------
__global__ void __launch_bounds__(256) median_kernel(
    const float* __restrict__ yhat, float* __restrict__ out)
{
  __shared__ float vals[4][100];
  const int wave = threadIdx.x >> 6, lane = threadIdx.x & 63;
  const int cell = blockIdx.x * 4 + wave;
  const int b = cell / TM1, t = cell - b * TM1;
  const float* basep = yhat + (size_t)b * NSAMP * TM1 + t;
  const float v1 = basep[(size_t)lane * TM1];
  vals[wave][lane] = v1;
  float v2 = 0.f;
  if (lane < 36) { v2 = basep[(size_t)(64 + lane) * TM1]; vals[wave][64 + lane] = v2; }
  __syncthreads();
  int cl1 = 0, ce1 = 0, cl2 = 0, ce2 = 0;
  for (int jj = 0; jj < 100; jj++) {
    const float w = vals[wave][jj];
    cl1 += (w < v1); ce1 += (w == v1);
    cl2 += (w < v2); ce2 += (w == v2);
  }
  if (cl1 <= 49 && 49 < cl1 + ce1) out[cell] = v1;
  if (lane < 36 && cl2 <= 49 && 49 < cl2 + ce2) out[cell] = v2;
}

// ---------------- launch ----------------
extern "C" void kernel_launch(void* const* d_in, const int* in_sizes, int n_in,
                              void* d_out, int out_size, void* d_ws, size_t ws_size,
                              hipStream_t stream) {
  (void)in_sizes; (void)n_in; (void)out_size; (void)ws_size;
  const float* X     = (const float*)d_in[0];
  const float* Wih0  = (const float*)d_in[2];
  const float* Whh0  = (const float*)d_in[3];
  const float* bih0  = (const float*)d_in[4];
  const float* bhh0  = (const float*)d_in[5];
  const float* Wih1  = (const float*)d_in[6];
  const float* Whh1  = (const float*)d_in[7];
  const float* bih1  = (const float*)d_in[8];
  const float* bhh1  = (const float*)d_in[9];
  const float* wdf   = (const float*)d_in[10];
  const float* bdf   = (const float*)d_in[11];
  const float* wloc  = (const float*)d_in[12];
  const float* bloc  = (const float*)d_in[13];
  const float* wsc   = (const float*)d_in[14];
  const float* bsc   = (const float*)d_in[15];
  const float* emb   = (const float*)d_in[16];

  float* wsf = (float*)d_ws;
  float* inp  = wsf + OFF_INP;
  float* ct   = wsf + OFF_CT;
  float* ts   = wsf + OFF_TS;
  float* lts  = wsf + OFF_LTS;
  float* dfp  = wsf + OFF_DF;
  float* locp = wsf + OFF_LOC;
  float* scp  = wsf + OFF_SC;
  float* h0f  = wsf + OFF_H0F;
  float* c0f  = wsf + OFF_C0F;
  float* h1f  = wsf + OFF_H1F;
  float* c1f  = wsf + OFF_C1F;
  float* yhat = wsf + OFF_YH;
  float* h0r  = wsf + OFF_H0R;
  float* c0r  = wsf + OFF_C0R;
  float* h1r  = wsf + OFF_H1R;
  float* c1r  = wsf + OFF_C1R;
  float* bufg = wsf + OFF_BUF;
  float* prev = wsf + OFF_PREV;

  const u32 key0 = 0u, key1 = 42u;
  u32 kc0, kc1, kl0, kl1;
  jx_subkey(key0, key1, 2u, 0u, kc0, kc1);
  jx_subkey(key0, key1, 2u, 1u, kl0, kl1);
  u32 kz0, kz1, kg0, kg1;
  jx_subkey(kc0, kc1, 2u, 0u, kz0, kz1);
  jx_subkey(kc0, kc1, 2u, 1u, kg0, kg1);

  prep_kernel<<<NB, 256, 0, stream>>>(X, emb, inp, ct, ts, lts);
  ctx_lstm_kernel<<<NB, 256, 0, stream>>>(inp, Wih0, Whh0, bih0, bhh0, Wih1, Whh1, bih1, bhh1,
                                          wdf, bdf, wloc, bloc, wsc, bsc,
                                          dfp, locp, scp, h0f, c0f, h1f, c1f);
  ctx_sample_kernel<<<NCTXS / 256, 256, 0, stream>>>(dfp, locp, scp, ts, yhat, kz0, kz1, kg0, kg1);
  dec_init_kernel<<<(RTOT * 64) / 256, 256, 0, stream>>>(h0f, c0f, h1f, c1f, ct, yhat,
                                                         h0r, c0r, h1r, c1r, bufg, prev);
  for (int s = 0; s < NSTEP; s++) {
    u32 ks0, ks1;
    jx_subkey(kl0, kl1, (u32)NSTEP, (u32)s, ks0, ks1);
    u32 skz0, skz1, skg0, skg1;
    jx_subkey(ks0, ks1, 2u, 0u, skz0, skz1);
    jx_subkey(ks0, ks1, 2u, 1u, skg0, skg1);
    dec_step_kernel<<<RTOT / 16, 256, 0, stream>>>(inp, ts, Wih0, Whh0, bih0, bhh0, Wih1, Whh1,
                                                   bih1, bhh1, wdf, bdf, wloc, bloc, wsc, bsc,
                                                   h0r, c0r, h1r, c1r, bufg, prev, yhat,
                                                   s, skz0, skz1, skg0, skg1);
  }
  median_kernel<<<(NB * TM1) / 4, 256, 0, stream>>>(yhat, (float*)d_out);
}